// Round 24
// baseline (393.036 us; speedup 1.0000x reference)
//
#include <hip/hip_runtime.h>

#define N_NODES 50000
#define N_EDGES 800000
#define D 64
#define NCHUNK 64
#define CHUNK_E (N_EDGES / NCHUNK)   // 12500 edges per chunk
#define NRANGE 4
#define RANGE_N 16384                // nodes per range; packed u16 pairs in 32KB LDS
#define NB_NODE 196                  // ceil(50001/256)
#define PLACE_BLOCKS (N_EDGES / 256) // 3125 exact
#define FLAGBIT 0x80000000u
#define SREP 16                      // diagnostic repetition of k_scan only

typedef int iv4 __attribute__((ext_vector_type(4)));

__device__ __forceinline__ unsigned short f2bf(float f) {   // RNE float->bf16
    unsigned int u = __float_as_uint(f);
    u += 0x7FFFu + ((u >> 16) & 1u);
    return (unsigned short)(u >> 16);
}
__device__ __forceinline__ float bf2f(unsigned int s) {     // low 16 bits -> float
    return __uint_as_float(s << 16);
}

// ---------- packed-u16 LDS histogram + local ranks; block 0 zeroes SREP flag sets ----------
__global__ __launch_bounds__(1024) void k_hist(const int* __restrict__ col,
                                               unsigned short* __restrict__ part,
                                               unsigned short* __restrict__ lrank,
                                               unsigned int* __restrict__ partials) {
    __shared__ unsigned int h[RANGE_N / 2];   // 32 KiB
    int i = blockIdx.x >> 2;   // chunk 0..63
    int j = blockIdx.x & 3;    // range 0..3
    int t = threadIdx.x;
    if (blockIdx.x == 0)
        for (int k = t; k < SREP * 256; k += 1024) partials[k] = 0;   // clear all rep flags
    for (int k = t; k < RANGE_N / 2; k += 1024) h[k] = 0;
    __syncthreads();
    int base = i * CHUNK_E;
    for (int e = base + t; e < base + CHUNK_E; e += 1024) {
        int c = col[e];
        if ((c >> 14) == j) {
            int local = c & (RANGE_N - 1);
            int sh = (local & 1) << 4;
            unsigned int lr = atomicAdd(&h[local >> 1], 1u << sh);
            lrank[e] = (unsigned short)((lr >> sh) & 0xffffu);
        }
    }
    __syncthreads();
    for (int k = t; k < RANGE_N; k += 1024) {
        int n = j * RANGE_N + k;
        if (n < N_NODES)
            part[(size_t)i * N_NODES + n] =
                (unsigned short)((h[k >> 1] >> ((k & 1) << 4)) & 0xffffu);
    }
}

// ---------- scan (REP'd, NON-destructive: prefixes -> part2; per-rep flag region) ----------
__global__ __launch_bounds__(256) void k_scan(const unsigned short* __restrict__ part,
                                              unsigned short* __restrict__ part2,
                                              int* __restrict__ start,
                                              unsigned int* __restrict__ partials) {
    __shared__ int s[256];
    __shared__ int red[256];
    int b = blockIdx.x, t = threadIdx.x;
    int n = b * 256 + t;
#pragma unroll 1
    for (int rep = 0; rep < SREP; ++rep) {
        asm volatile("" ::: "memory");
        unsigned int* flags = partials + rep * 256;
        unsigned int run = 0;
        if (n < N_NODES) {
            unsigned int vals[NCHUNK];
#pragma unroll
            for (int i = 0; i < NCHUNK; ++i)
                vals[i] = part[(size_t)i * N_NODES + n];   // all 64 loads in flight
#pragma unroll
            for (int i = 0; i < NCHUNK; ++i) {
                part2[(size_t)i * N_NODES + n] = (unsigned short)run;
                run += vals[i];
            }
        }
        int cnt = (n < N_NODES) ? (int)run : 0;
        s[t] = cnt;
        __syncthreads();
        for (int off = 1; off < 256; off <<= 1) {
            int a = (t >= off) ? s[t - off] : 0;
            __syncthreads();
            s[t] += a;
            __syncthreads();
        }
        if (t == 255)
            __hip_atomic_store(&flags[b], (unsigned int)s[255] | FLAGBIT,
                               __ATOMIC_RELEASE, __HIP_MEMORY_SCOPE_AGENT);
        unsigned int pv = 0;
        if (t < b) {
            unsigned int v;
            do {
                v = __hip_atomic_load(&flags[t], __ATOMIC_ACQUIRE, __HIP_MEMORY_SCOPE_AGENT);
            } while (!(v & FLAGBIT));
            pv = v & ~FLAGBIT;
        }
        red[t] = (int)pv;
        __syncthreads();
        for (int off = 128; off > 0; off >>= 1) {
            if (t < off) red[t] += red[t + off];
            __syncthreads();
        }
        int offset = red[0];
        if (n <= N_NODES) start[n] = offset + s[t] - cnt;
        __syncthreads();   // protect s/red before next rep
    }
}

// ---------- place 4-byte records (u16 src | bf16 ew); reads part2 ----------
__global__ __launch_bounds__(256) void k_place(const int* __restrict__ ei,
                                               const float* __restrict__ ew,
                                               const int* __restrict__ start,
                                               const unsigned short* __restrict__ part2,
                                               const unsigned short* __restrict__ lrank,
                                               unsigned int* __restrict__ rec) {
    int e = blockIdx.x * 256 + threadIdx.x;   // 3125*256 = 800000 exact
    int c = ei[N_EDGES + e];
    int i = e / CHUNK_E;   // compile-time magic-div
    int pos = start[c] + (int)part2[(size_t)i * N_NODES + c] + (int)lrank[e];
    rec[pos] = (unsigned int)ei[e] | ((unsigned int)f2bf(ew[e]) << 16);
}

// ---------- xw16 = bf16( dis[row] * (x @ W) ), deg/dis fused in ----------
__global__ __launch_bounds__(256, 4) void k_xw(const float* __restrict__ x,
                                               const float* __restrict__ W,
                                               const int* __restrict__ start,
                                               const unsigned int* __restrict__ rec,
                                               float* __restrict__ dis,
                                               unsigned short* __restrict__ xw16) {
    __shared__ float Ws[64 * 64];   // 16 KiB
    __shared__ float dls[64];
    int t = threadIdx.x;
    int r0 = blockIdx.x * 64;
    for (int i = t; i < 1024; i += 256)
        ((float4*)Ws)[i] = ((const float4*)W)[i];

    {
        int q = t >> 2, l = t & 3;
        int node = r0 + q;
        float s = 0.f;
        if (node < N_NODES) {
            int j0 = start[node], j1 = start[node + 1];
            for (int j = j0 + l; j < j1; j += 4) s += bf2f(rec[j] >> 16);
        }
        s += __shfl_xor(s, 1);
        s += __shfl_xor(s, 2);
        if (l == 0 && node < N_NODES) {
            float dv = rsqrtf(1.0f + s);   // self-loop weight 1
            dls[q] = dv;
            dis[node] = dv;
        }
    }
    __syncthreads();

    int cg = t & 15;
    int rg = t >> 4;
    int ra = min(r0 + rg,      N_NODES - 1);
    int rb = min(r0 + rg + 16, N_NODES - 1);
    int rc = min(r0 + rg + 32, N_NODES - 1);
    int rd = min(r0 + rg + 48, N_NODES - 1);
    const float4* x4 = (const float4*)x;

    float4 acc0 = make_float4(0.f, 0.f, 0.f, 0.f);
    float4 acc1 = acc0, acc2 = acc0, acc3 = acc0;

#pragma unroll 1
    for (int k4 = 0; k4 < 16; ++k4) {
        float4 xv0 = x4[ra * 16 + k4];
        float4 xv1 = x4[rb * 16 + k4];
        float4 xv2 = x4[rc * 16 + k4];
        float4 xv3 = x4[rd * 16 + k4];
        float4 w0 = *(const float4*)&Ws[(k4 * 4 + 0) * 64 + cg * 4];
        float4 w1 = *(const float4*)&Ws[(k4 * 4 + 1) * 64 + cg * 4];
        float4 w2 = *(const float4*)&Ws[(k4 * 4 + 2) * 64 + cg * 4];
        float4 w3 = *(const float4*)&Ws[(k4 * 4 + 3) * 64 + cg * 4];
        acc0.x = fmaf(xv0.x, w0.x, acc0.x); acc0.y = fmaf(xv0.x, w0.y, acc0.y);
        acc0.z = fmaf(xv0.x, w0.z, acc0.z); acc0.w = fmaf(xv0.x, w0.w, acc0.w);
        acc0.x = fmaf(xv0.y, w1.x, acc0.x); acc0.y = fmaf(xv0.y, w1.y, acc0.y);
        acc0.z = fmaf(xv0.y, w1.z, acc0.z); acc0.w = fmaf(xv0.y, w1.w, acc0.w);
        acc0.x = fmaf(xv0.z, w2.x, acc0.x); acc0.y = fmaf(xv0.z, w2.y, acc0.y);
        acc0.z = fmaf(xv0.z, w2.z, acc0.z); acc0.w = fmaf(xv0.z, w2.w, acc0.w);
        acc0.x = fmaf(xv0.w, w3.x, acc0.x); acc0.y = fmaf(xv0.w, w3.y, acc0.y);
        acc0.z = fmaf(xv0.w, w3.z, acc0.z); acc0.w = fmaf(xv0.w, w3.w, acc0.w);
        acc1.x = fmaf(xv1.x, w0.x, acc1.x); acc1.y = fmaf(xv1.x, w0.y, acc1.y);
        acc1.z = fmaf(xv1.x, w0.z, acc1.z); acc1.w = fmaf(xv1.x, w0.w, acc1.w);
        acc1.x = fmaf(xv1.y, w1.x, acc1.x); acc1.y = fmaf(xv1.y, w1.y, acc1.y);
        acc1.z = fmaf(xv1.y, w1.z, acc1.z); acc1.w = fmaf(xv1.y, w1.w, acc1.w);
        acc1.x = fmaf(xv1.z, w2.x, acc1.x); acc1.y = fmaf(xv1.z, w2.y, acc1.y);
        acc1.z = fmaf(xv1.z, w2.z, acc1.z); acc1.w = fmaf(xv1.z, w2.w, acc1.w);
        acc1.x = fmaf(xv1.w, w3.x, acc1.x); acc1.y = fmaf(xv1.w, w3.y, acc1.y);
        acc1.z = fmaf(xv1.w, w3.z, acc1.z); acc1.w = fmaf(xv1.w, w3.w, acc1.w);
        acc2.x = fmaf(xv2.x, w0.x, acc2.x); acc2.y = fmaf(xv2.x, w0.y, acc2.y);
        acc2.z = fmaf(xv2.x, w0.z, acc2.z); acc2.w = fmaf(xv2.x, w0.w, acc2.w);
        acc2.x = fmaf(xv2.y, w1.x, acc2.x); acc2.y = fmaf(xv2.y, w1.y, acc2.y);
        acc2.z = fmaf(xv2.y, w1.z, acc2.z); acc2.w = fmaf(xv2.y, w1.w, acc2.w);
        acc2.x = fmaf(xv2.z, w2.x, acc2.x); acc2.y = fmaf(xv2.z, w2.y, acc2.y);
        acc2.z = fmaf(xv2.z, w2.z, acc2.z); acc2.w = fmaf(xv2.z, w2.w, acc2.w);
        acc2.x = fmaf(xv2.w, w3.x, acc2.x); acc2.y = fmaf(xv2.w, w3.y, acc2.y);
        acc2.z = fmaf(xv2.w, w3.z, acc2.z); acc2.w = fmaf(xv2.w, w3.w, acc2.w);
        acc3.x = fmaf(xv3.x, w0.x, acc3.x); acc3.y = fmaf(xv3.x, w0.y, acc3.y);
        acc3.z = fmaf(xv3.x, w0.z, acc3.z); acc3.w = fmaf(xv3.x, w0.w, acc3.w);
        acc3.x = fmaf(xv3.y, w1.x, acc3.x); acc3.y = fmaf(xv3.y, w1.y, acc3.y);
        acc3.z = fmaf(xv3.y, w1.z, acc3.z); acc3.w = fmaf(xv3.y, w1.w, acc3.w);
        acc3.x = fmaf(xv3.z, w2.x, acc3.x); acc3.y = fmaf(xv3.z, w2.y, acc3.y);
        acc3.z = fmaf(xv3.z, w2.z, acc3.z); acc3.w = fmaf(xv3.z, w2.w, acc3.w);
        acc3.x = fmaf(xv3.w, w3.x, acc3.x); acc3.y = fmaf(xv3.w, w3.y, acc3.y);
        acc3.z = fmaf(xv3.w, w3.z, acc3.z); acc3.w = fmaf(xv3.w, w3.w, acc3.w);
    }

    float4 accs[4] = { acc0, acc1, acc2, acc3 };
#pragma unroll
    for (int i = 0; i < 4; ++i) {
        int row = r0 + rg + 16 * i;
        if (row < N_NODES) {
            float s = dls[rg + 16 * i];
            ushort4 s4 = make_ushort4(f2bf(accs[i].x * s), f2bf(accs[i].y * s),
                                      f2bf(accs[i].z * s), f2bf(accs[i].w * s));
            *(ushort4*)&xw16[row * 64 + cg * 4] = s4;
        }
    }
}

// ---------- gather: one wave per node, SCALARIZED records (SALU unpack/mask) ----------
__global__ __launch_bounds__(256) void k_gather(const int* __restrict__ start,
                                                const unsigned int* __restrict__ rec,
                                                const unsigned short* __restrict__ xw16,
                                                const float* __restrict__ dis,
                                                const float* __restrict__ bias,
                                                float* __restrict__ out) {
    int wave = threadIdx.x >> 6;
    int c = threadIdx.x & 63;
    int n = blockIdx.x * 4 + wave;   // 12500 * 4 = 50000 exact
    float di = dis[n];
    float acc[8];
#pragma unroll
    for (int k = 0; k < 8; ++k) acc[k] = 0.f;
    acc[0] = bf2f((unsigned int)xw16[n * 64 + c]);   // self-loop (xw pre-scaled by dis)
    int j0  = __builtin_amdgcn_readfirstlane(start[n]);       // SGPR
    int cnt = __builtin_amdgcn_readfirstlane(start[n + 1]) - j0;
    int nit = (cnt + 7) >> 3;
    const iv4* rq = (const iv4*)(rec + j0);                   // scalar base
    for (int it = 0; it < nit; ++it) {
        iv4 qa = rq[2 * it], qb = rq[2 * it + 1];   // uniform addr (over-read safe/masked)
        unsigned int r[8];
        r[0] = (unsigned int)__builtin_amdgcn_readfirstlane(qa.x);
        r[1] = (unsigned int)__builtin_amdgcn_readfirstlane(qa.y);
        r[2] = (unsigned int)__builtin_amdgcn_readfirstlane(qa.z);
        r[3] = (unsigned int)__builtin_amdgcn_readfirstlane(qa.w);
        r[4] = (unsigned int)__builtin_amdgcn_readfirstlane(qb.x);
        r[5] = (unsigned int)__builtin_amdgcn_readfirstlane(qb.y);
        r[6] = (unsigned int)__builtin_amdgcn_readfirstlane(qb.z);
        r[7] = (unsigned int)__builtin_amdgcn_readfirstlane(qb.w);
        float v[8];
#pragma unroll
        for (int k = 0; k < 8; ++k)
            v[k] = bf2f((unsigned int)xw16[(r[k] & 0xffffu) * 64 + c]);
        int rem = cnt - (it << 3);
#pragma unroll
        for (int k = 0; k < 8; ++k) {
            float w = (k < rem) ? bf2f(r[k] >> 16) : 0.0f;
            acc[k] = fmaf(v[k], w, acc[k]);
        }
    }
    float a = ((acc[0] + acc[1]) + (acc[2] + acc[3])) + ((acc[4] + acc[5]) + (acc[6] + acc[7]));
    out[n * 64 + c] = fmaf(a, di, bias[c]);
}

extern "C" void kernel_launch(void* const* d_in, const int* in_sizes, int n_in,
                              void* d_out, int out_size, void* d_ws, size_t ws_size,
                              hipStream_t stream) {
    const float* x    = (const float*)d_in[0];
    const float* W    = (const float*)d_in[1];
    const float* bias = (const float*)d_in[2];
    const float* ew   = (const float*)d_in[3];
    const int*   ei   = (const int*)d_in[4];   // (2,E) flat: [0:E) src, [E:2E) dst
    float* out = (float*)d_out;

    // ---- workspace layout (bytes) ----
    char* wsb = (char*)d_ws;
    unsigned int*   rec   = (unsigned int*)wsb;                 //  3.2 MB used + slack
    unsigned short* xw16  = (unsigned short*)(wsb + 6200000);   //  6.4 MB
    unsigned short* lrank = (unsigned short*)(wsb + 12600000);  //  1.6 MB
    unsigned short* part  = (unsigned short*)(wsb + 14200000);  //  6.4 MB
    unsigned short* part2 = (unsigned short*)(wsb + 20600000);  //  6.4 MB
    float*          dis   = (float*)(wsb + 27000000);           //  200 KB
    int*            start = (int*)(wsb + 27200000);             //  200 KB (+4)
    unsigned int*   partials = (unsigned int*)(wsb + 27400016); //  16 KB (SREP x 256)

    k_hist<<<NCHUNK * NRANGE, 1024, 0, stream>>>(ei + N_EDGES, part, lrank, partials);
    k_scan<<<NB_NODE, 256, 0, stream>>>(part, part2, start, partials);
    k_place<<<PLACE_BLOCKS, 256, 0, stream>>>(ei, ew, start, part2, lrank, rec);
    k_xw<<<(N_NODES + 63) / 64, 256, 0, stream>>>(x, W, start, rec, dis, xw16);
    k_gather<<<N_NODES / 4, 256, 0, stream>>>(start, rec, xw16, dis, bias, out);
}

// Round 25
// 157.884 us; speedup vs baseline: 2.4894x; 2.4894x over previous
//
#include <hip/hip_runtime.h>

#define N_NODES 50000
#define N_EDGES 800000
#define D 64
#define NCHUNK 64
#define CHUNK_E (N_EDGES / NCHUNK)   // 12500 edges per chunk
#define NRANGE 4
#define RANGE_N 16384                // nodes per range; packed u16 pairs in 32KB LDS
#define SCAN_BLOCKS 782              // 782*64 = 50048 >= 50001 nodes(+boundary)
#define PLACE_BLOCKS (N_EDGES / 256) // 3125 exact
#define FLAGBIT 0x80000000u

typedef int iv4 __attribute__((ext_vector_type(4)));

__device__ __forceinline__ unsigned short f2bf(float f) {   // RNE float->bf16
    unsigned int u = __float_as_uint(f);
    u += 0x7FFFu + ((u >> 16) & 1u);
    return (unsigned short)(u >> 16);
}
__device__ __forceinline__ float bf2f(unsigned int s) {     // low 16 bits -> float
    return __uint_as_float(s << 16);
}

// ---------- packed-u16 LDS histogram + local ranks; block 0 zeroes scan flags ----------
__global__ __launch_bounds__(1024) void k_hist(const int* __restrict__ col,
                                               unsigned short* __restrict__ part,
                                               unsigned short* __restrict__ lrank,
                                               unsigned int* __restrict__ partials) {
    __shared__ unsigned int h[RANGE_N / 2];   // 32 KiB
    int i = blockIdx.x >> 2;   // chunk 0..63
    int j = blockIdx.x & 3;    // range 0..3
    int t = threadIdx.x;
    if (blockIdx.x == 0 && t < 1024) partials[t] = 0;   // clear 1024 lookback flags
    for (int k = t; k < RANGE_N / 2; k += 1024) h[k] = 0;
    __syncthreads();
    int base = i * CHUNK_E;
    for (int e = base + t; e < base + CHUNK_E; e += 1024) {
        int c = col[e];
        if ((c >> 14) == j) {
            int local = c & (RANGE_N - 1);
            int sh = (local & 1) << 4;
            unsigned int lr = atomicAdd(&h[local >> 1], 1u << sh);
            lrank[e] = (unsigned short)((lr >> sh) & 0xffffu);
        }
    }
    __syncthreads();
    for (int k = t; k < RANGE_N; k += 1024) {
        int n = j * RANGE_N + k;
        if (n < N_NODES)
            part[(size_t)i * N_NODES + n] =
                (unsigned short)((h[k >> 1] >> ((k & 1) << 4)) & 0xffffu);
    }
}

// ---------- scan: 4 threads/node (16 chunks each), quad-shuffle combine, lookback ----------
// 782 blocks; __launch_bounds__(256,6) -> >=6 blocks/CU * 256 CUs = 1536 slots,
// all blocks co-resident -> lookback spin cannot deadlock.
__global__ __launch_bounds__(256, 6) void k_scan(unsigned short* __restrict__ part,
                                                 int* __restrict__ start,
                                                 unsigned int* __restrict__ partials) {
    __shared__ int snode[64];
    __shared__ int sred[256];
    int b = blockIdx.x, t = threadIdx.x;
    int q = t >> 2, l = t & 3;
    int n = b * 64 + q;
    unsigned int vals[16];
    unsigned int lsum = 0;
    if (n < N_NODES) {
#pragma unroll
        for (int i = 0; i < 16; ++i) {
            vals[i] = part[(size_t)(l * 16 + i) * N_NODES + n];   // 16 loads in flight
            lsum += vals[i];
        }
    }
    // width-4 inclusive scan over the 4 lanes of this node
    unsigned int x = lsum;
    unsigned int y = __shfl_up(x, 1, 4); if (l >= 1) x += y;
    y = __shfl_up(x, 2, 4); if (l >= 2) x += y;
    unsigned int excl = x - lsum;            // chunk-group base within node
    unsigned int cnt = __shfl(x, 3, 4);      // node total (broadcast lane 3 of quad)
    if (n < N_NODES) {
        unsigned int run = excl;
#pragma unroll
        for (int i = 0; i < 16; ++i) {       // in-place: counts -> within-node prefixes
            part[(size_t)(l * 16 + i) * N_NODES + n] = (unsigned short)run;
            run += vals[i];
        }
    }
    if (l == 0) snode[q] = (n < N_NODES) ? (int)cnt : 0;
    __syncthreads();
    // 64-wide wave shuffle-scan of the block's node totals (threads 0..63 = wave 0)
    if (t < 64) {
        int v = snode[t];
        int ix = v;
        for (int off = 1; off < 64; off <<= 1) {
            int u = __shfl_up(ix, off, 64);
            if (t >= off) ix += u;
        }
        snode[t] = ix - v;   // exclusive prefix within block
        if (t == 63)
            __hip_atomic_store(&partials[b], (unsigned int)ix | FLAGBIT,
                               __ATOMIC_RELEASE, __HIP_MEMORY_SCOPE_AGENT);
    }
    // lookback: sum totals of blocks 0..b-1 (strided spin across 256 threads)
    int psum = 0;
    for (int t2 = t; t2 < b; t2 += 256) {
        unsigned int v;
        do {
            v = __hip_atomic_load(&partials[t2], __ATOMIC_ACQUIRE, __HIP_MEMORY_SCOPE_AGENT);
        } while (!(v & FLAGBIT));
        psum += (int)(v & ~FLAGBIT);
    }
    sred[t] = psum;
    __syncthreads();
    for (int off = 128; off > 0; off >>= 1) {
        if (t < off) sred[t] += sred[t + off];
        __syncthreads();
    }
    int offset = sred[0];
    if (l == 0 && n <= N_NODES) start[n] = offset + snode[q];
}

// ---------- place 4-byte records (u16 src | bf16 ew); exact permutation, no pads ----------
__global__ __launch_bounds__(256) void k_place(const int* __restrict__ ei,
                                               const float* __restrict__ ew,
                                               const int* __restrict__ start,
                                               const unsigned short* __restrict__ part,
                                               const unsigned short* __restrict__ lrank,
                                               unsigned int* __restrict__ rec) {
    int e = blockIdx.x * 256 + threadIdx.x;   // 3125*256 = 800000 exact
    int c = ei[N_EDGES + e];
    int i = e / CHUNK_E;   // compile-time magic-div
    int pos = start[c] + (int)part[(size_t)i * N_NODES + c] + (int)lrank[e];
    rec[pos] = (unsigned int)ei[e] | ((unsigned int)f2bf(ew[e]) << 16);
}

// ---------- xw16 = bf16( dis[row] * (x @ W) ), deg/dis fused in ----------
__global__ __launch_bounds__(256, 4) void k_xw(const float* __restrict__ x,
                                               const float* __restrict__ W,
                                               const int* __restrict__ start,
                                               const unsigned int* __restrict__ rec,
                                               float* __restrict__ dis,
                                               unsigned short* __restrict__ xw16) {
    __shared__ float Ws[64 * 64];   // 16 KiB
    __shared__ float dls[64];
    int t = threadIdx.x;
    int r0 = blockIdx.x * 64;
    for (int i = t; i < 1024; i += 256)
        ((float4*)Ws)[i] = ((const float4*)W)[i];

    {
        int q = t >> 2, l = t & 3;
        int node = r0 + q;
        float s = 0.f;
        if (node < N_NODES) {
            int j0 = start[node], j1 = start[node + 1];
            for (int j = j0 + l; j < j1; j += 4) s += bf2f(rec[j] >> 16);
        }
        s += __shfl_xor(s, 1);
        s += __shfl_xor(s, 2);
        if (l == 0 && node < N_NODES) {
            float dv = rsqrtf(1.0f + s);   // self-loop weight 1
            dls[q] = dv;
            dis[node] = dv;
        }
    }
    __syncthreads();

    int cg = t & 15;
    int rg = t >> 4;
    int ra = min(r0 + rg,      N_NODES - 1);
    int rb = min(r0 + rg + 16, N_NODES - 1);
    int rc = min(r0 + rg + 32, N_NODES - 1);
    int rd = min(r0 + rg + 48, N_NODES - 1);
    const float4* x4 = (const float4*)x;

    float4 acc0 = make_float4(0.f, 0.f, 0.f, 0.f);
    float4 acc1 = acc0, acc2 = acc0, acc3 = acc0;

#pragma unroll 1
    for (int k4 = 0; k4 < 16; ++k4) {
        float4 xv0 = x4[ra * 16 + k4];
        float4 xv1 = x4[rb * 16 + k4];
        float4 xv2 = x4[rc * 16 + k4];
        float4 xv3 = x4[rd * 16 + k4];
        float4 w0 = *(const float4*)&Ws[(k4 * 4 + 0) * 64 + cg * 4];
        float4 w1 = *(const float4*)&Ws[(k4 * 4 + 1) * 64 + cg * 4];
        float4 w2 = *(const float4*)&Ws[(k4 * 4 + 2) * 64 + cg * 4];
        float4 w3 = *(const float4*)&Ws[(k4 * 4 + 3) * 64 + cg * 4];
        acc0.x = fmaf(xv0.x, w0.x, acc0.x); acc0.y = fmaf(xv0.x, w0.y, acc0.y);
        acc0.z = fmaf(xv0.x, w0.z, acc0.z); acc0.w = fmaf(xv0.x, w0.w, acc0.w);
        acc0.x = fmaf(xv0.y, w1.x, acc0.x); acc0.y = fmaf(xv0.y, w1.y, acc0.y);
        acc0.z = fmaf(xv0.y, w1.z, acc0.z); acc0.w = fmaf(xv0.y, w1.w, acc0.w);
        acc0.x = fmaf(xv0.z, w2.x, acc0.x); acc0.y = fmaf(xv0.z, w2.y, acc0.y);
        acc0.z = fmaf(xv0.z, w2.z, acc0.z); acc0.w = fmaf(xv0.z, w2.w, acc0.w);
        acc0.x = fmaf(xv0.w, w3.x, acc0.x); acc0.y = fmaf(xv0.w, w3.y, acc0.y);
        acc0.z = fmaf(xv0.w, w3.z, acc0.z); acc0.w = fmaf(xv0.w, w3.w, acc0.w);
        acc1.x = fmaf(xv1.x, w0.x, acc1.x); acc1.y = fmaf(xv1.x, w0.y, acc1.y);
        acc1.z = fmaf(xv1.x, w0.z, acc1.z); acc1.w = fmaf(xv1.x, w0.w, acc1.w);
        acc1.x = fmaf(xv1.y, w1.x, acc1.x); acc1.y = fmaf(xv1.y, w1.y, acc1.y);
        acc1.z = fmaf(xv1.y, w1.z, acc1.z); acc1.w = fmaf(xv1.y, w1.w, acc1.w);
        acc1.x = fmaf(xv1.z, w2.x, acc1.x); acc1.y = fmaf(xv1.z, w2.y, acc1.y);
        acc1.z = fmaf(xv1.z, w2.z, acc1.z); acc1.w = fmaf(xv1.z, w2.w, acc1.w);
        acc1.x = fmaf(xv1.w, w3.x, acc1.x); acc1.y = fmaf(xv1.w, w3.y, acc1.y);
        acc1.z = fmaf(xv1.w, w3.z, acc1.z); acc1.w = fmaf(xv1.w, w3.w, acc1.w);
        acc2.x = fmaf(xv2.x, w0.x, acc2.x); acc2.y = fmaf(xv2.x, w0.y, acc2.y);
        acc2.z = fmaf(xv2.x, w0.z, acc2.z); acc2.w = fmaf(xv2.x, w0.w, acc2.w);
        acc2.x = fmaf(xv2.y, w1.x, acc2.x); acc2.y = fmaf(xv2.y, w1.y, acc2.y);
        acc2.z = fmaf(xv2.y, w1.z, acc2.z); acc2.w = fmaf(xv2.y, w1.w, acc2.w);
        acc2.x = fmaf(xv2.z, w2.x, acc2.x); acc2.y = fmaf(xv2.z, w2.y, acc2.y);
        acc2.z = fmaf(xv2.z, w2.z, acc2.z); acc2.w = fmaf(xv2.z, w2.w, acc2.w);
        acc2.x = fmaf(xv2.w, w3.x, acc2.x); acc2.y = fmaf(xv2.w, w3.y, acc2.y);
        acc2.z = fmaf(xv2.w, w3.z, acc2.z); acc2.w = fmaf(xv2.w, w3.w, acc2.w);
        acc3.x = fmaf(xv3.x, w0.x, acc3.x); acc3.y = fmaf(xv3.x, w0.y, acc3.y);
        acc3.z = fmaf(xv3.x, w0.z, acc3.z); acc3.w = fmaf(xv3.x, w0.w, acc3.w);
        acc3.x = fmaf(xv3.y, w1.x, acc3.x); acc3.y = fmaf(xv3.y, w1.y, acc3.y);
        acc3.z = fmaf(xv3.y, w1.z, acc3.z); acc3.w = fmaf(xv3.y, w1.w, acc3.w);
        acc3.x = fmaf(xv3.z, w2.x, acc3.x); acc3.y = fmaf(xv3.z, w2.y, acc3.y);
        acc3.z = fmaf(xv3.z, w2.z, acc3.z); acc3.w = fmaf(xv3.z, w2.w, acc3.w);
        acc3.x = fmaf(xv3.w, w3.x, acc3.x); acc3.y = fmaf(xv3.w, w3.y, acc3.y);
        acc3.z = fmaf(xv3.w, w3.z, acc3.z); acc3.w = fmaf(xv3.w, w3.w, acc3.w);
    }

    float4 accs[4] = { acc0, acc1, acc2, acc3 };
#pragma unroll
    for (int i = 0; i < 4; ++i) {
        int row = r0 + rg + 16 * i;
        if (row < N_NODES) {
            float s = dls[rg + 16 * i];
            ushort4 s4 = make_ushort4(f2bf(accs[i].x * s), f2bf(accs[i].y * s),
                                      f2bf(accs[i].z * s), f2bf(accs[i].w * s));
            *(ushort4*)&xw16[row * 64 + cg * 4] = s4;
        }
    }
}

// ---------- gather: one wave per node, SCALARIZED records (SALU unpack/mask) ----------
__global__ __launch_bounds__(256) void k_gather(const int* __restrict__ start,
                                                const unsigned int* __restrict__ rec,
                                                const unsigned short* __restrict__ xw16,
                                                const float* __restrict__ dis,
                                                const float* __restrict__ bias,
                                                float* __restrict__ out) {
    int wave = threadIdx.x >> 6;
    int c = threadIdx.x & 63;
    int n = blockIdx.x * 4 + wave;   // 12500 * 4 = 50000 exact
    float di = dis[n];
    float acc[8];
#pragma unroll
    for (int k = 0; k < 8; ++k) acc[k] = 0.f;
    acc[0] = bf2f((unsigned int)xw16[n * 64 + c]);   // self-loop (xw pre-scaled by dis)
    int j0  = __builtin_amdgcn_readfirstlane(start[n]);       // SGPR
    int cnt = __builtin_amdgcn_readfirstlane(start[n + 1]) - j0;
    int nit = (cnt + 7) >> 3;
    const iv4* rq = (const iv4*)(rec + j0);                   // scalar base
    for (int it = 0; it < nit; ++it) {
        iv4 qa = rq[2 * it], qb = rq[2 * it + 1];   // uniform addr (over-read safe/masked)
        unsigned int r[8];
        r[0] = (unsigned int)__builtin_amdgcn_readfirstlane(qa.x);
        r[1] = (unsigned int)__builtin_amdgcn_readfirstlane(qa.y);
        r[2] = (unsigned int)__builtin_amdgcn_readfirstlane(qa.z);
        r[3] = (unsigned int)__builtin_amdgcn_readfirstlane(qa.w);
        r[4] = (unsigned int)__builtin_amdgcn_readfirstlane(qb.x);
        r[5] = (unsigned int)__builtin_amdgcn_readfirstlane(qb.y);
        r[6] = (unsigned int)__builtin_amdgcn_readfirstlane(qb.z);
        r[7] = (unsigned int)__builtin_amdgcn_readfirstlane(qb.w);
        float v[8];
#pragma unroll
        for (int k = 0; k < 8; ++k)
            v[k] = bf2f((unsigned int)xw16[(r[k] & 0xffffu) * 64 + c]);
        int rem = cnt - (it << 3);
#pragma unroll
        for (int k = 0; k < 8; ++k) {
            float w = (k < rem) ? bf2f(r[k] >> 16) : 0.0f;
            acc[k] = fmaf(v[k], w, acc[k]);
        }
    }
    float a = ((acc[0] + acc[1]) + (acc[2] + acc[3])) + ((acc[4] + acc[5]) + (acc[6] + acc[7]));
    out[n * 64 + c] = fmaf(a, di, bias[c]);
}

extern "C" void kernel_launch(void* const* d_in, const int* in_sizes, int n_in,
                              void* d_out, int out_size, void* d_ws, size_t ws_size,
                              hipStream_t stream) {
    const float* x    = (const float*)d_in[0];
    const float* W    = (const float*)d_in[1];
    const float* bias = (const float*)d_in[2];
    const float* ew   = (const float*)d_in[3];
    const int*   ei   = (const int*)d_in[4];   // (2,E) flat: [0:E) src, [E:2E) dst
    float* out = (float*)d_out;

    // ---- workspace layout (bytes) ----
    char* wsb = (char*)d_ws;
    unsigned int*   rec   = (unsigned int*)wsb;                 //  3.2 MB used + slack
    unsigned short* xw16  = (unsigned short*)(wsb + 6200000);   //  6.4 MB
    unsigned short* lrank = (unsigned short*)(wsb + 12600000);  //  1.6 MB
    unsigned short* part  = (unsigned short*)(wsb + 14200000);  //  6.4 MB
    float*          dis   = (float*)(wsb + 20600000);           //  200 KB
    int*            start = (int*)(wsb + 21000000);             //  200 KB (+4)
    unsigned int*   partials = (unsigned int*)(wsb + 21300000); //  4 KB (1024 flags)

    k_hist<<<NCHUNK * NRANGE, 1024, 0, stream>>>(ei + N_EDGES, part, lrank, partials);
    k_scan<<<SCAN_BLOCKS, 256, 0, stream>>>(part, start, partials);
    k_place<<<PLACE_BLOCKS, 256, 0, stream>>>(ei, ew, start, part, lrank, rec);
    k_xw<<<(N_NODES + 63) / 64, 256, 0, stream>>>(x, W, start, rec, dis, xw16);
    k_gather<<<N_NODES / 4, 256, 0, stream>>>(start, rec, xw16, dis, bias, out);
}

// Round 26
// 81.768 us; speedup vs baseline: 4.8067x; 1.9309x over previous
//
#include <hip/hip_runtime.h>

#define N_NODES 50000
#define N_EDGES 800000
#define D 64
#define NCHUNK 64
#define CHUNK_E (N_EDGES / NCHUNK)   // 12500 edges per chunk
#define NRANGE 4
#define RANGE_N 16384                // nodes per range; packed u16 pairs in 32KB LDS
#define SCANA_BLOCKS 782             // 782*64 = 50048 >= 50000 nodes
#define NB_NODE 196                  // ceil(50001/256)
#define PLACE_BLOCKS (N_EDGES / 256) // 3125 exact

typedef int iv4 __attribute__((ext_vector_type(4)));

__device__ __forceinline__ unsigned short f2bf(float f) {   // RNE float->bf16
    unsigned int u = __float_as_uint(f);
    u += 0x7FFFu + ((u >> 16) & 1u);
    return (unsigned short)(u >> 16);
}
__device__ __forceinline__ float bf2f(unsigned int s) {     // low 16 bits -> float
    return __uint_as_float(s << 16);
}

// ---------- packed-u16 LDS histogram + local ranks ----------
__global__ __launch_bounds__(1024) void k_hist(const int* __restrict__ col,
                                               unsigned short* __restrict__ part,
                                               unsigned short* __restrict__ lrank) {
    __shared__ unsigned int h[RANGE_N / 2];   // 32 KiB
    int i = blockIdx.x >> 2;   // chunk 0..63
    int j = blockIdx.x & 3;    // range 0..3
    int t = threadIdx.x;
    for (int k = t; k < RANGE_N / 2; k += 1024) h[k] = 0;
    __syncthreads();
    int base = i * CHUNK_E;
    for (int e = base + t; e < base + CHUNK_E; e += 1024) {
        int c = col[e];
        if ((c >> 14) == j) {
            int local = c & (RANGE_N - 1);
            int sh = (local & 1) << 4;
            unsigned int lr = atomicAdd(&h[local >> 1], 1u << sh);
            lrank[e] = (unsigned short)((lr >> sh) & 0xffffu);
        }
    }
    __syncthreads();
    for (int k = t; k < RANGE_N; k += 1024) {
        int n = j * RANGE_N + k;
        if (n < N_NODES)
            part[(size_t)i * N_NODES + n] =
                (unsigned short)((h[k >> 1] >> ((k & 1) << 4)) & 0xffffu);
    }
}

// ---------- scan A: 4 threads/node, within-node chunk prefixes + node totals ----------
// 782 blocks, no inter-block sync (kernel boundary is the sync).
__global__ __launch_bounds__(256) void k_scanA(unsigned short* __restrict__ part,
                                               int* __restrict__ nodecnt) {
    int b = blockIdx.x, t = threadIdx.x;
    int q = t >> 2, l = t & 3;
    int n = b * 64 + q;
    if (n >= N_NODES) return;
    unsigned int vals[16];
    unsigned int lsum = 0;
#pragma unroll
    for (int i = 0; i < 16; ++i) {
        vals[i] = part[(size_t)(l * 16 + i) * N_NODES + n];   // 16 loads in flight
        lsum += vals[i];
    }
    // width-4 inclusive scan across the node's 4 lanes
    unsigned int x = lsum;
    unsigned int y = __shfl_up(x, 1, 4); if (l >= 1) x += y;
    y = __shfl_up(x, 2, 4); if (l >= 2) x += y;
    unsigned int excl = x - lsum;
    unsigned int run = excl;
#pragma unroll
    for (int i = 0; i < 16; ++i) {       // in place: counts -> within-node prefixes
        part[(size_t)(l * 16 + i) * N_NODES + n] = (unsigned short)run;
        run += vals[i];
    }
    if (l == 3) nodecnt[n] = (int)x;     // node total (inclusive over 4 lanes)
}

// ---------- scan B: block-local exclusive scan of node counts + block totals ----------
__global__ __launch_bounds__(256) void k_scanB(const int* __restrict__ nodecnt,
                                               int* __restrict__ start,
                                               int* __restrict__ partials) {
    __shared__ int s[256];
    int b = blockIdx.x, t = threadIdx.x;
    int n = b * 256 + t;
    int cnt = (n < N_NODES) ? nodecnt[n] : 0;
    s[t] = cnt;
    __syncthreads();
    for (int off = 1; off < 256; off <<= 1) {
        int a = (t >= off) ? s[t - off] : 0;
        __syncthreads();
        s[t] += a;
        __syncthreads();
    }
    if (n <= N_NODES) start[n] = s[t] - cnt;   // block-local exclusive prefix
    if (t == 255) partials[b] = s[255];
}

// ---------- scan C: add block-offset (plain loads; kernel boundary = sync) ----------
__global__ __launch_bounds__(256) void k_scanC(int* __restrict__ start,
                                               const int* __restrict__ partials) {
    __shared__ int red[256];
    int b = blockIdx.x, t = threadIdx.x;
    red[t] = (t < b) ? partials[t] : 0;   // b <= 195 < 256
    __syncthreads();
    for (int off = 128; off > 0; off >>= 1) {
        if (t < off) red[t] += red[t + off];
        __syncthreads();
    }
    int offset = red[0];
    int n = b * 256 + t;
    if (n <= N_NODES) start[n] += offset;
}

// ---------- place 4-byte records (u16 src | bf16 ew); exact permutation, no pads ----------
__global__ __launch_bounds__(256) void k_place(const int* __restrict__ ei,
                                               const float* __restrict__ ew,
                                               const int* __restrict__ start,
                                               const unsigned short* __restrict__ part,
                                               const unsigned short* __restrict__ lrank,
                                               unsigned int* __restrict__ rec) {
    int e = blockIdx.x * 256 + threadIdx.x;   // 3125*256 = 800000 exact
    int c = ei[N_EDGES + e];
    int i = e / CHUNK_E;   // compile-time magic-div
    int pos = start[c] + (int)part[(size_t)i * N_NODES + c] + (int)lrank[e];
    rec[pos] = (unsigned int)ei[e] | ((unsigned int)f2bf(ew[e]) << 16);
}

// ---------- xw16 = bf16( dis[row] * (x @ W) ), deg/dis fused in ----------
__global__ __launch_bounds__(256, 4) void k_xw(const float* __restrict__ x,
                                               const float* __restrict__ W,
                                               const int* __restrict__ start,
                                               const unsigned int* __restrict__ rec,
                                               float* __restrict__ dis,
                                               unsigned short* __restrict__ xw16) {
    __shared__ float Ws[64 * 64];   // 16 KiB
    __shared__ float dls[64];
    int t = threadIdx.x;
    int r0 = blockIdx.x * 64;
    for (int i = t; i < 1024; i += 256)
        ((float4*)Ws)[i] = ((const float4*)W)[i];

    {
        int q = t >> 2, l = t & 3;
        int node = r0 + q;
        float s = 0.f;
        if (node < N_NODES) {
            int j0 = start[node], j1 = start[node + 1];
            for (int j = j0 + l; j < j1; j += 4) s += bf2f(rec[j] >> 16);
        }
        s += __shfl_xor(s, 1);
        s += __shfl_xor(s, 2);
        if (l == 0 && node < N_NODES) {
            float dv = rsqrtf(1.0f + s);   // self-loop weight 1
            dls[q] = dv;
            dis[node] = dv;
        }
    }
    __syncthreads();

    int cg = t & 15;
    int rg = t >> 4;
    int ra = min(r0 + rg,      N_NODES - 1);
    int rb = min(r0 + rg + 16, N_NODES - 1);
    int rc = min(r0 + rg + 32, N_NODES - 1);
    int rd = min(r0 + rg + 48, N_NODES - 1);
    const float4* x4 = (const float4*)x;

    float4 acc0 = make_float4(0.f, 0.f, 0.f, 0.f);
    float4 acc1 = acc0, acc2 = acc0, acc3 = acc0;

#pragma unroll 1
    for (int k4 = 0; k4 < 16; ++k4) {
        float4 xv0 = x4[ra * 16 + k4];
        float4 xv1 = x4[rb * 16 + k4];
        float4 xv2 = x4[rc * 16 + k4];
        float4 xv3 = x4[rd * 16 + k4];
        float4 w0 = *(const float4*)&Ws[(k4 * 4 + 0) * 64 + cg * 4];
        float4 w1 = *(const float4*)&Ws[(k4 * 4 + 1) * 64 + cg * 4];
        float4 w2 = *(const float4*)&Ws[(k4 * 4 + 2) * 64 + cg * 4];
        float4 w3 = *(const float4*)&Ws[(k4 * 4 + 3) * 64 + cg * 4];
        acc0.x = fmaf(xv0.x, w0.x, acc0.x); acc0.y = fmaf(xv0.x, w0.y, acc0.y);
        acc0.z = fmaf(xv0.x, w0.z, acc0.z); acc0.w = fmaf(xv0.x, w0.w, acc0.w);
        acc0.x = fmaf(xv0.y, w1.x, acc0.x); acc0.y = fmaf(xv0.y, w1.y, acc0.y);
        acc0.z = fmaf(xv0.y, w1.z, acc0.z); acc0.w = fmaf(xv0.y, w1.w, acc0.w);
        acc0.x = fmaf(xv0.z, w2.x, acc0.x); acc0.y = fmaf(xv0.z, w2.y, acc0.y);
        acc0.z = fmaf(xv0.z, w2.z, acc0.z); acc0.w = fmaf(xv0.z, w2.w, acc0.w);
        acc0.x = fmaf(xv0.w, w3.x, acc0.x); acc0.y = fmaf(xv0.w, w3.y, acc0.y);
        acc0.z = fmaf(xv0.w, w3.z, acc0.z); acc0.w = fmaf(xv0.w, w3.w, acc0.w);
        acc1.x = fmaf(xv1.x, w0.x, acc1.x); acc1.y = fmaf(xv1.x, w0.y, acc1.y);
        acc1.z = fmaf(xv1.x, w0.z, acc1.z); acc1.w = fmaf(xv1.x, w0.w, acc1.w);
        acc1.x = fmaf(xv1.y, w1.x, acc1.x); acc1.y = fmaf(xv1.y, w1.y, acc1.y);
        acc1.z = fmaf(xv1.y, w1.z, acc1.z); acc1.w = fmaf(xv1.y, w1.w, acc1.w);
        acc1.x = fmaf(xv1.z, w2.x, acc1.x); acc1.y = fmaf(xv1.z, w2.y, acc1.y);
        acc1.z = fmaf(xv1.z, w2.z, acc1.z); acc1.w = fmaf(xv1.z, w2.w, acc1.w);
        acc1.x = fmaf(xv1.w, w3.x, acc1.x); acc1.y = fmaf(xv1.w, w3.y, acc1.y);
        acc1.z = fmaf(xv1.w, w3.z, acc1.z); acc1.w = fmaf(xv1.w, w3.w, acc1.w);
        acc2.x = fmaf(xv2.x, w0.x, acc2.x); acc2.y = fmaf(xv2.x, w0.y, acc2.y);
        acc2.z = fmaf(xv2.x, w0.z, acc2.z); acc2.w = fmaf(xv2.x, w0.w, acc2.w);
        acc2.x = fmaf(xv2.y, w1.x, acc2.x); acc2.y = fmaf(xv2.y, w1.y, acc2.y);
        acc2.z = fmaf(xv2.y, w1.z, acc2.z); acc2.w = fmaf(xv2.y, w1.w, acc2.w);
        acc2.x = fmaf(xv2.z, w2.x, acc2.x); acc2.y = fmaf(xv2.z, w2.y, acc2.y);
        acc2.z = fmaf(xv2.z, w2.z, acc2.z); acc2.w = fmaf(xv2.z, w2.w, acc2.w);
        acc2.x = fmaf(xv2.w, w3.x, acc2.x); acc2.y = fmaf(xv2.w, w3.y, acc2.y);
        acc2.z = fmaf(xv2.w, w3.z, acc2.z); acc2.w = fmaf(xv2.w, w3.w, acc2.w);
        acc3.x = fmaf(xv3.x, w0.x, acc3.x); acc3.y = fmaf(xv3.x, w0.y, acc3.y);
        acc3.z = fmaf(xv3.x, w0.z, acc3.z); acc3.w = fmaf(xv3.x, w0.w, acc3.w);
        acc3.x = fmaf(xv3.y, w1.x, acc3.x); acc3.y = fmaf(xv3.y, w1.y, acc3.y);
        acc3.z = fmaf(xv3.y, w1.z, acc3.z); acc3.w = fmaf(xv3.y, w1.w, acc3.w);
        acc3.x = fmaf(xv3.z, w2.x, acc3.x); acc3.y = fmaf(xv3.z, w2.y, acc3.y);
        acc3.z = fmaf(xv3.z, w2.z, acc3.z); acc3.w = fmaf(xv3.z, w2.w, acc3.w);
        acc3.x = fmaf(xv3.w, w3.x, acc3.x); acc3.y = fmaf(xv3.w, w3.y, acc3.y);
        acc3.z = fmaf(xv3.w, w3.z, acc3.z); acc3.w = fmaf(xv3.w, w3.w, acc3.w);
    }

    float4 accs[4] = { acc0, acc1, acc2, acc3 };
#pragma unroll
    for (int i = 0; i < 4; ++i) {
        int row = r0 + rg + 16 * i;
        if (row < N_NODES) {
            float s = dls[rg + 16 * i];
            ushort4 s4 = make_ushort4(f2bf(accs[i].x * s), f2bf(accs[i].y * s),
                                      f2bf(accs[i].z * s), f2bf(accs[i].w * s));
            *(ushort4*)&xw16[row * 64 + cg * 4] = s4;
        }
    }
}

// ---------- gather: one wave per node, SCALARIZED records (SALU unpack/mask) ----------
__global__ __launch_bounds__(256) void k_gather(const int* __restrict__ start,
                                                const unsigned int* __restrict__ rec,
                                                const unsigned short* __restrict__ xw16,
                                                const float* __restrict__ dis,
                                                const float* __restrict__ bias,
                                                float* __restrict__ out) {
    int wave = threadIdx.x >> 6;
    int c = threadIdx.x & 63;
    int n = blockIdx.x * 4 + wave;   // 12500 * 4 = 50000 exact
    float di = dis[n];
    float acc[8];
#pragma unroll
    for (int k = 0; k < 8; ++k) acc[k] = 0.f;
    acc[0] = bf2f((unsigned int)xw16[n * 64 + c]);   // self-loop (xw pre-scaled by dis)
    int j0  = __builtin_amdgcn_readfirstlane(start[n]);       // SGPR
    int cnt = __builtin_amdgcn_readfirstlane(start[n + 1]) - j0;
    int nit = (cnt + 7) >> 3;
    const iv4* rq = (const iv4*)(rec + j0);                   // scalar base
    for (int it = 0; it < nit; ++it) {
        iv4 qa = rq[2 * it], qb = rq[2 * it + 1];   // uniform addr (over-read safe/masked)
        unsigned int r[8];
        r[0] = (unsigned int)__builtin_amdgcn_readfirstlane(qa.x);
        r[1] = (unsigned int)__builtin_amdgcn_readfirstlane(qa.y);
        r[2] = (unsigned int)__builtin_amdgcn_readfirstlane(qa.z);
        r[3] = (unsigned int)__builtin_amdgcn_readfirstlane(qa.w);
        r[4] = (unsigned int)__builtin_amdgcn_readfirstlane(qb.x);
        r[5] = (unsigned int)__builtin_amdgcn_readfirstlane(qb.y);
        r[6] = (unsigned int)__builtin_amdgcn_readfirstlane(qb.z);
        r[7] = (unsigned int)__builtin_amdgcn_readfirstlane(qb.w);
        float v[8];
#pragma unroll
        for (int k = 0; k < 8; ++k)
            v[k] = bf2f((unsigned int)xw16[(r[k] & 0xffffu) * 64 + c]);
        int rem = cnt - (it << 3);
#pragma unroll
        for (int k = 0; k < 8; ++k) {
            float w = (k < rem) ? bf2f(r[k] >> 16) : 0.0f;
            acc[k] = fmaf(v[k], w, acc[k]);
        }
    }
    float a = ((acc[0] + acc[1]) + (acc[2] + acc[3])) + ((acc[4] + acc[5]) + (acc[6] + acc[7]));
    out[n * 64 + c] = fmaf(a, di, bias[c]);
}

extern "C" void kernel_launch(void* const* d_in, const int* in_sizes, int n_in,
                              void* d_out, int out_size, void* d_ws, size_t ws_size,
                              hipStream_t stream) {
    const float* x    = (const float*)d_in[0];
    const float* W    = (const float*)d_in[1];
    const float* bias = (const float*)d_in[2];
    const float* ew   = (const float*)d_in[3];
    const int*   ei   = (const int*)d_in[4];   // (2,E) flat: [0:E) src, [E:2E) dst
    float* out = (float*)d_out;

    // ---- workspace layout (bytes) ----
    char* wsb = (char*)d_ws;
    unsigned int*   rec   = (unsigned int*)wsb;                 //  3.2 MB used + slack
    unsigned short* xw16  = (unsigned short*)(wsb + 6200000);   //  6.4 MB
    unsigned short* lrank = (unsigned short*)(wsb + 12600000);  //  1.6 MB
    unsigned short* part  = (unsigned short*)(wsb + 14200000);  //  6.4 MB
    float*          dis   = (float*)(wsb + 20600000);           //  200 KB
    int*            start = (int*)(wsb + 21000000);             //  200 KB (+4)
    int*            nodecnt = (int*)(wsb + 21300000);           //  200 KB
    int*            partials = (int*)(wsb + 21600000);          //  784 B

    k_hist<<<NCHUNK * NRANGE, 1024, 0, stream>>>(ei + N_EDGES, part, lrank);
    k_scanA<<<SCANA_BLOCKS, 256, 0, stream>>>(part, nodecnt);
    k_scanB<<<NB_NODE, 256, 0, stream>>>(nodecnt, start, partials);
    k_scanC<<<NB_NODE, 256, 0, stream>>>(start, partials);
    k_place<<<PLACE_BLOCKS, 256, 0, stream>>>(ei, ew, start, part, lrank, rec);
    k_xw<<<(N_NODES + 63) / 64, 256, 0, stream>>>(x, W, start, rec, dis, xw16);
    k_gather<<<N_NODES / 4, 256, 0, stream>>>(start, rec, xw16, dis, bias, out);
}